// Round 7
// baseline (5462.338 us; speedup 1.0000x reference)
//
#include <hip/hip_runtime.h>
#include <stdint.h>

typedef int i32x4 __attribute__((ext_vector_type(4)));

#define M_DIM 8192
#define N_DIM 16384
#define K_DIM 4096

#define BM 128
#define BN 128
#define BK 64

__device__ __forceinline__ void gload_lds16(const void* g, void* l) {
  __builtin_amdgcn_global_load_lds((const __attribute__((address_space(1))) void*)g,
                                   (__attribute__((address_space(3))) void*)l,
                                   16, 0, 0);
}

// ---------------- Pass 1: sum|W| (double) + max|x| (uint-ordered float) ----------------
__global__ __launch_bounds__(256) void reduce_kernel(const float* __restrict__ W,
                                                     const float* __restrict__ x,
                                                     double* __restrict__ gsum,
                                                     unsigned* __restrict__ xmax,
                                                     int nW4, int nX4) {
  int tid = blockIdx.x * blockDim.x + threadIdx.x;
  int stride = gridDim.x * blockDim.x;
  const float4* W4 = (const float4*)W;
  const float4* X4 = (const float4*)x;
  double s = 0.0;
  for (int i = tid; i < nW4; i += stride) {
    float4 v = W4[i];
    s += (double)fabsf(v.x) + (double)fabsf(v.y) +
         (double)fabsf(v.z) + (double)fabsf(v.w);
  }
  float m = 0.f;
  for (int i = tid; i < nX4; i += stride) {
    float4 v = X4[i];
    m = fmaxf(m, fmaxf(fmaxf(fabsf(v.x), fabsf(v.y)), fmaxf(fabsf(v.z), fabsf(v.w))));
  }
  for (int off = 32; off > 0; off >>= 1) {
    s += __shfl_down(s, off, 64);
    m = fmaxf(m, __shfl_down(m, off, 64));
  }
  __shared__ double wsum[4];
  __shared__ float wmax[4];
  int l = threadIdx.x & 63, w = threadIdx.x >> 6;
  if (l == 0) { wsum[w] = s; wmax[w] = m; }
  __syncthreads();
  if (threadIdx.x == 0) {
    atomicAdd(gsum, wsum[0] + wsum[1] + wsum[2] + wsum[3]);
    float mm = fmaxf(fmaxf(wmax[0], wmax[1]), fmaxf(wmax[2], wmax[3]));
    atomicMax(xmax, __float_as_uint(mm));  // positive floats: uint order == float order
  }
}

// ---------------- Pass 2 (fused): quantize W -> i8  AND  split x -> i8 hi/lo ----------
__global__ __launch_bounds__(256) void prep_kernel(const float* __restrict__ W,
                                                   const float* __restrict__ x,
                                                   const double* __restrict__ gsum,
                                                   const unsigned* __restrict__ xmax,
                                                   char* __restrict__ Bq,
                                                   char* __restrict__ hi,
                                                   char* __restrict__ lo,
                                                   int nW4, int nX4) {
  float gamma = (float)(*gsum * (1.0 / (double)((size_t)N_DIM * K_DIM))) + 1e-6f;
  float amax = __uint_as_float(*xmax);
  float inv = 32512.f / (amax + 1e-30f);   // |q| <= 32512 = 127*256
  int tid = blockIdx.x * blockDim.x + threadIdx.x;
  int stride = gridDim.x * blockDim.x;
  const float4* W4 = (const float4*)W;
  const float4* X4 = (const float4*)x;
  char4* B4 = (char4*)Bq;
  char4* H4 = (char4*)hi;
  char4* L4 = (char4*)lo;
  for (int i = tid; i < nW4; i += stride) {
    float4 v = W4[i];
    // identical fp32 math to the verified rounds (same gamma-threshold behavior)
    float q0 = copysignf(fminf(rintf(fabsf(v.x / gamma)), 1.0f), v.x);
    float q1 = copysignf(fminf(rintf(fabsf(v.y / gamma)), 1.0f), v.y);
    float q2 = copysignf(fminf(rintf(fabsf(v.z / gamma)), 1.0f), v.z);
    float q3 = copysignf(fminf(rintf(fabsf(v.w / gamma)), 1.0f), v.w);
    char4 o;
    o.x = (char)(int)q0; o.y = (char)(int)q1;
    o.z = (char)(int)q2; o.w = (char)(int)q3;
    B4[i] = o;
  }
  for (int i = tid; i < nX4; i += stride) {
    float4 v = X4[i];
    float q[4] = {v.x, v.y, v.z, v.w};
    char hh[4], ll[4];
#pragma unroll
    for (int j = 0; j < 4; ++j) {
      float qf = fminf(fmaxf(rintf(q[j] * inv), -32512.f), 32512.f);
      float hf = rintf(qf * (1.f / 256.f));
      float lf = qf - 256.f * hf;
      if (lf > 127.f) { hf += 1.f; lf -= 256.f; }   // keep l in [-128,127]
      hh[j] = (char)(int)hf;
      ll[j] = (char)(int)lf;
    }
    char4 h = {hh[0], hh[1], hh[2], hh[3]};
    char4 l = {ll[0], ll[1], ll[2], ll[3]};
    H4[i] = h;
    L4[i] = l;
  }
}

// ---------------- Pass 3: GEMM  C = s*(256*Ah + Al) . Bq^T  (i8 MFMA, i32 acc) --------
// 8 waves x 64x32 output each. Fragment-order LDS (conflict-free, linear dest).
// T3-minimum prefetch dbuf: issue next tile's loads -> compute current -> vmcnt(0)+barrier.
__global__ __launch_bounds__(512, 6) void gemm_kernel(const char* __restrict__ Ahi,
                                                      const char* __restrict__ Alo,
                                                      const char* __restrict__ Bq,
                                                      const unsigned* __restrict__ xmax,
                                                      float* __restrict__ C) {
  __shared__ __align__(16) char lds[49152];  // 2 x 24576: Ahi[0,8K) Alo[8K,16K) B[16K,24K)

  int wg = blockIdx.x;
  wg = (wg & 7) * 1024 + (wg >> 3);   // XCD swizzle, 8192 % 8 == 0 -> bijective
  const int tm = wg >> 7;             // 64 row tiles
  const int tn = wg & 127;            // 128 col tiles

  const int tid = threadIdx.x;
  const int w = tid >> 6;             // 0..7
  const int l = tid & 63;
  const int wr = w >> 2;              // 0..1 : A rows wr*64
  const int wc = w & 3;               // 0..3 : B rows wc*32
  const int lr15 = l & 15;
  const int lk16 = (l >> 4) << 4;     // 0,16,32,48

  // 24 subtile staging jobs (Ahi 0-7, Alo 8-15, B 16-23); wave w owns jobs 3w..3w+2.
  // Global src is the fragment-order per-lane permutation; LDS dest linear (rule #21).
  const char* srcs[3];
  int jobs[3];
#pragma unroll
  for (int j = 0; j < 3; ++j) {
    int job = w * 3 + j;
    jobs[j] = job;
    const char* base = (job < 8) ? Ahi : (job < 16) ? Alo : Bq;
    int s = job & 7;
    int rowb = (job < 16) ? tm * BM : tn * BN;
    srcs[j] = base + (size_t)(rowb + s * 16 + lr15) * K_DIM + lk16;
  }

  i32x4 acch[4][2], accl[4][2];
#pragma unroll
  for (int m = 0; m < 4; ++m)
#pragma unroll
    for (int n = 0; n < 2; ++n) {
      acch[m][n] = (i32x4){0, 0, 0, 0};
      accl[m][n] = (i32x4){0, 0, 0, 0};
    }

  // prologue: stage tile 0 into buf0, drain, barrier
#pragma unroll
  for (int j = 0; j < 3; ++j)
    gload_lds16(srcs[j], (void*)&lds[jobs[j] * 1024]);
  asm volatile("s_waitcnt vmcnt(0)" ::: "memory");
  __builtin_amdgcn_s_barrier();

  for (int t = 0; t < K_DIM / BK; ++t) {
    const int cur = (t & 1) * 24576;
    const int nxt = 24576 - cur;
    if (t < K_DIM / BK - 1) {
      const int k0 = (t + 1) * BK;
#pragma unroll
      for (int j = 0; j < 3; ++j)
        gload_lds16(srcs[j] + k0, (void*)&lds[nxt + jobs[j] * 1024]);
    }

    i32x4 b0 = *(const i32x4*)&lds[cur + 16384 + (wc * 2 + 0) * 1024 + l * 16];
    i32x4 b1 = *(const i32x4*)&lds[cur + 16384 + (wc * 2 + 1) * 1024 + l * 16];
    __builtin_amdgcn_s_setprio(1);
#pragma unroll
    for (int m = 0; m < 4; ++m) {
      i32x4 a = *(const i32x4*)&lds[cur + (wr * 4 + m) * 1024 + l * 16];
      acch[m][0] = __builtin_amdgcn_mfma_i32_16x16x64_i8(a, b0, acch[m][0], 0, 0, 0);
      acch[m][1] = __builtin_amdgcn_mfma_i32_16x16x64_i8(a, b1, acch[m][1], 0, 0, 0);
    }
#pragma unroll
    for (int m = 0; m < 4; ++m) {
      i32x4 a = *(const i32x4*)&lds[cur + 8192 + (wr * 4 + m) * 1024 + l * 16];
      accl[m][0] = __builtin_amdgcn_mfma_i32_16x16x64_i8(a, b0, accl[m][0], 0, 0, 0);
      accl[m][1] = __builtin_amdgcn_mfma_i32_16x16x64_i8(a, b1, accl[m][1], 0, 0, 0);
    }
    __builtin_amdgcn_s_setprio(0);

    // next tile's loads fully landed (latency hidden under the MFMA cluster above);
    // single barrier also closes the read-of-cur vs overwrite-next-iter hazard.
    asm volatile("s_waitcnt vmcnt(0)" ::: "memory");
    __builtin_amdgcn_s_barrier();
  }

  const float sc = __uint_as_float(*xmax) * (1.f / 32512.f);
  // D mapping (shape-determined): col = lane&15, row = (lane>>4)*4 + j
#pragma unroll
  for (int m = 0; m < 4; ++m) {
    int row = tm * BM + wr * 64 + m * 16 + (l >> 4) * 4;
#pragma unroll
    for (int n = 0; n < 2; ++n) {
      int col = tn * BN + wc * 32 + n * 16 + lr15;
      float* cp = C + (size_t)row * N_DIM + col;
#pragma unroll
      for (int j = 0; j < 4; ++j)
        cp[(size_t)j * N_DIM] = sc * fmaf(256.f, (float)acch[m][n][j], (float)accl[m][n][j]);
    }
  }
}

extern "C" void kernel_launch(void* const* d_in, const int* in_sizes, int n_in,
                              void* d_out, int out_size, void* d_ws, size_t ws_size,
                              hipStream_t stream) {
  const float* x = (const float*)d_in[0];   // [4,2048,4096] fp32 -> [8192][4096]
  const float* W = (const float*)d_in[1];   // [16384,4096] fp32
  float* C = (float*)d_out;                 // [8192][16384] fp32

  double* gsum = (double*)d_ws;
  unsigned* xmax = (unsigned*)((char*)d_ws + 8);
  char* Ahi = (char*)d_ws + 256;
  char* Alo = Ahi + (size_t)M_DIM * K_DIM;          // 32 MB each
  char* Bq  = Alo + (size_t)M_DIM * K_DIM;          // 64 MB
  // ws: 256 B + 32 + 32 + 64 MB = 128 MB

  // zero BOTH scalars: ws is re-poisoned to 0xAA (0xAAAAAAAA would win atomicMax!)
  hipMemsetAsync(d_ws, 0, 16, stream);
  reduce_kernel<<<dim3(2048), dim3(256), 0, stream>>>(W, x, gsum, xmax,
                                                      (N_DIM * K_DIM) / 4,
                                                      (M_DIM * K_DIM) / 4);
  prep_kernel<<<dim3(2048), dim3(256), 0, stream>>>(W, x, gsum, xmax, Bq, Ahi, Alo,
                                                    (N_DIM * K_DIM) / 4,
                                                    (M_DIM * K_DIM) / 4);
  gemm_kernel<<<dim3((M_DIM / BM) * (N_DIM / BN)), dim3(512), 0, stream>>>(Ahi, Alo, Bq, xmax, C);
}

// Round 8
// 2258.899 us; speedup vs baseline: 2.4181x; 2.4181x over previous
//
#include <hip/hip_runtime.h>
#include <stdint.h>

typedef int i32x4 __attribute__((ext_vector_type(4)));

#define M_DIM 8192
#define N_DIM 16384
#define K_DIM 4096

#define BM 128
#define BN 128
#define BK 64

__device__ __forceinline__ void gload_lds16(const void* g, void* l) {
  __builtin_amdgcn_global_load_lds((const __attribute__((address_space(1))) void*)g,
                                   (__attribute__((address_space(3))) void*)l,
                                   16, 0, 0);
}

// ---------------- Pass 1: sum|W| (double) + max|x| (uint-ordered float) ----------------
__global__ __launch_bounds__(256) void reduce_kernel(const float* __restrict__ W,
                                                     const float* __restrict__ x,
                                                     double* __restrict__ gsum,
                                                     unsigned* __restrict__ xmax,
                                                     int nW4, int nX4) {
  int tid = blockIdx.x * blockDim.x + threadIdx.x;
  int stride = gridDim.x * blockDim.x;
  const float4* W4 = (const float4*)W;
  const float4* X4 = (const float4*)x;
  double s = 0.0;
  for (int i = tid; i < nW4; i += stride) {
    float4 v = W4[i];
    s += (double)fabsf(v.x) + (double)fabsf(v.y) +
         (double)fabsf(v.z) + (double)fabsf(v.w);
  }
  float m = 0.f;
  for (int i = tid; i < nX4; i += stride) {
    float4 v = X4[i];
    m = fmaxf(m, fmaxf(fmaxf(fabsf(v.x), fabsf(v.y)), fmaxf(fabsf(v.z), fabsf(v.w))));
  }
  for (int off = 32; off > 0; off >>= 1) {
    s += __shfl_down(s, off, 64);
    m = fmaxf(m, __shfl_down(m, off, 64));
  }
  __shared__ double wsum[4];
  __shared__ float wmax[4];
  int l = threadIdx.x & 63, w = threadIdx.x >> 6;
  if (l == 0) { wsum[w] = s; wmax[w] = m; }
  __syncthreads();
  if (threadIdx.x == 0) {
    atomicAdd(gsum, wsum[0] + wsum[1] + wsum[2] + wsum[3]);
    float mm = fmaxf(fmaxf(wmax[0], wmax[1]), fmaxf(wmax[2], wmax[3]));
    atomicMax(xmax, __float_as_uint(mm));  // positive floats: uint order == float order
  }
}

// ---------------- Pass 2 (fused): quantize W -> i8  AND  split x -> i8 hi/lo ----------
__global__ __launch_bounds__(256) void prep_kernel(const float* __restrict__ W,
                                                   const float* __restrict__ x,
                                                   const double* __restrict__ gsum,
                                                   const unsigned* __restrict__ xmax,
                                                   char* __restrict__ Bq,
                                                   char* __restrict__ hi,
                                                   char* __restrict__ lo,
                                                   int nW4, int nX4) {
  float gamma = (float)(*gsum * (1.0 / (double)((size_t)N_DIM * K_DIM))) + 1e-6f;
  float amax = __uint_as_float(*xmax);
  float inv = 32512.f / (amax + 1e-30f);   // |q| <= 32512 = 127*256
  int tid = blockIdx.x * blockDim.x + threadIdx.x;
  int stride = gridDim.x * blockDim.x;
  const float4* W4 = (const float4*)W;
  const float4* X4 = (const float4*)x;
  char4* B4 = (char4*)Bq;
  char4* H4 = (char4*)hi;
  char4* L4 = (char4*)lo;
  for (int i = tid; i < nW4; i += stride) {
    float4 v = W4[i];
    // identical fp32 math to the verified rounds (same gamma-threshold behavior)
    float q0 = copysignf(fminf(rintf(fabsf(v.x / gamma)), 1.0f), v.x);
    float q1 = copysignf(fminf(rintf(fabsf(v.y / gamma)), 1.0f), v.y);
    float q2 = copysignf(fminf(rintf(fabsf(v.z / gamma)), 1.0f), v.z);
    float q3 = copysignf(fminf(rintf(fabsf(v.w / gamma)), 1.0f), v.w);
    char4 o;
    o.x = (char)(int)q0; o.y = (char)(int)q1;
    o.z = (char)(int)q2; o.w = (char)(int)q3;
    B4[i] = o;
  }
  for (int i = tid; i < nX4; i += stride) {
    float4 v = X4[i];
    float q[4] = {v.x, v.y, v.z, v.w};
    char hh[4], ll[4];
#pragma unroll
    for (int j = 0; j < 4; ++j) {
      float qf = fminf(fmaxf(rintf(q[j] * inv), -32512.f), 32512.f);
      float hf = rintf(qf * (1.f / 256.f));
      float lf = qf - 256.f * hf;
      if (lf > 127.f) { hf += 1.f; lf -= 256.f; }   // keep l in [-128,127]
      hh[j] = (char)(int)hf;
      ll[j] = (char)(int)lf;
    }
    char4 h = {hh[0], hh[1], hh[2], hh[3]};
    char4 l = {ll[0], ll[1], ll[2], ll[3]};
    H4[i] = h;
    L4[i] = l;
  }
}

// ---------------- Pass 3: GEMM  C = s*(256*Ah + Al) . Bq^T  (i8 MFMA, i32 acc) --------
// 8 waves x 64x32 output each. Fragment-order LDS (conflict-free, linear dest).
// Prefetch dbuf: issue next tile's loads -> compute current -> vmcnt(0)+barrier.
// __launch_bounds__(512,4): VGPR cap 128 (NOT 6 -> cap 85 -> acc spill, round-7 lesson:
// WRITE_SIZE 0.5 -> 12.4 GB of scratch traffic, 3.2x regression).
__global__ __launch_bounds__(512, 4) void gemm_kernel(const char* __restrict__ Ahi,
                                                      const char* __restrict__ Alo,
                                                      const char* __restrict__ Bq,
                                                      const unsigned* __restrict__ xmax,
                                                      float* __restrict__ C) {
  __shared__ __align__(16) char lds[49152];  // 2 x 24576: Ahi[0,8K) Alo[8K,16K) B[16K,24K)

  int wg = blockIdx.x;
  wg = (wg & 7) * 1024 + (wg >> 3);   // XCD swizzle, 8192 % 8 == 0 -> bijective
  const int tm = wg >> 7;             // 64 row tiles
  const int tn = wg & 127;            // 128 col tiles

  const int tid = threadIdx.x;
  const int w = tid >> 6;             // 0..7
  const int l = tid & 63;
  const int wr = w >> 2;              // 0..1 : A rows wr*64
  const int wc = w & 3;               // 0..3 : B rows wc*32
  const int lr15 = l & 15;
  const int lk16 = (l >> 4) << 4;     // 0,16,32,48

  // 24 subtile staging jobs (Ahi 0-7, Alo 8-15, B 16-23); wave w owns jobs 3w..3w+2.
  // Global src is the fragment-order per-lane permutation; LDS dest linear (rule #21).
  const char* srcs[3];
  int jobs[3];
#pragma unroll
  for (int j = 0; j < 3; ++j) {
    int job = w * 3 + j;
    jobs[j] = job;
    const char* base = (job < 8) ? Ahi : (job < 16) ? Alo : Bq;
    int s = job & 7;
    int rowb = (job < 16) ? tm * BM : tn * BN;
    srcs[j] = base + (size_t)(rowb + s * 16 + lr15) * K_DIM + lk16;
  }

  i32x4 acch[4][2], accl[4][2];
#pragma unroll
  for (int m = 0; m < 4; ++m)
#pragma unroll
    for (int n = 0; n < 2; ++n) {
      acch[m][n] = (i32x4){0, 0, 0, 0};
      accl[m][n] = (i32x4){0, 0, 0, 0};
    }

  // prologue: stage tile 0 into buf0, drain, barrier
#pragma unroll
  for (int j = 0; j < 3; ++j)
    gload_lds16(srcs[j], (void*)&lds[jobs[j] * 1024]);
  asm volatile("s_waitcnt vmcnt(0)" ::: "memory");
  __builtin_amdgcn_s_barrier();

  for (int t = 0; t < K_DIM / BK; ++t) {
    const int cur = (t & 1) * 24576;
    const int nxt = 24576 - cur;
    if (t < K_DIM / BK - 1) {
      const int k0 = (t + 1) * BK;
#pragma unroll
      for (int j = 0; j < 3; ++j)
        gload_lds16(srcs[j] + k0, (void*)&lds[nxt + jobs[j] * 1024]);
    }

    i32x4 b0 = *(const i32x4*)&lds[cur + 16384 + (wc * 2 + 0) * 1024 + l * 16];
    i32x4 b1 = *(const i32x4*)&lds[cur + 16384 + (wc * 2 + 1) * 1024 + l * 16];
    __builtin_amdgcn_s_setprio(1);
#pragma unroll
    for (int m = 0; m < 4; ++m) {
      i32x4 a = *(const i32x4*)&lds[cur + (wr * 4 + m) * 1024 + l * 16];
      acch[m][0] = __builtin_amdgcn_mfma_i32_16x16x64_i8(a, b0, acch[m][0], 0, 0, 0);
      acch[m][1] = __builtin_amdgcn_mfma_i32_16x16x64_i8(a, b1, acch[m][1], 0, 0, 0);
    }
#pragma unroll
    for (int m = 0; m < 4; ++m) {
      i32x4 a = *(const i32x4*)&lds[cur + 8192 + (wr * 4 + m) * 1024 + l * 16];
      accl[m][0] = __builtin_amdgcn_mfma_i32_16x16x64_i8(a, b0, accl[m][0], 0, 0, 0);
      accl[m][1] = __builtin_amdgcn_mfma_i32_16x16x64_i8(a, b1, accl[m][1], 0, 0, 0);
    }
    __builtin_amdgcn_s_setprio(0);

    // next tile's loads fully landed (latency hidden under the MFMA cluster above);
    // single barrier also closes the read-of-cur vs overwrite-next-iter hazard.
    asm volatile("s_waitcnt vmcnt(0)" ::: "memory");
    __builtin_amdgcn_s_barrier();
  }

  const float sc = __uint_as_float(*xmax) * (1.f / 32512.f);
  // D mapping (shape-determined): col = lane&15, row = (lane>>4)*4 + j
#pragma unroll
  for (int m = 0; m < 4; ++m) {
    int row = tm * BM + wr * 64 + m * 16 + (l >> 4) * 4;
#pragma unroll
    for (int n = 0; n < 2; ++n) {
      int col = tn * BN + wc * 32 + n * 16 + lr15;
      float* cp = C + (size_t)row * N_DIM + col;
#pragma unroll
      for (int j = 0; j < 4; ++j)
        cp[(size_t)j * N_DIM] = sc * fmaf(256.f, (float)acch[m][n][j], (float)accl[m][n][j]);
    }
  }
}

extern "C" void kernel_launch(void* const* d_in, const int* in_sizes, int n_in,
                              void* d_out, int out_size, void* d_ws, size_t ws_size,
                              hipStream_t stream) {
  const float* x = (const float*)d_in[0];   // [4,2048,4096] fp32 -> [8192][4096]
  const float* W = (const float*)d_in[1];   // [16384,4096] fp32
  float* C = (float*)d_out;                 // [8192][16384] fp32

  double* gsum = (double*)d_ws;
  unsigned* xmax = (unsigned*)((char*)d_ws + 8);
  char* Ahi = (char*)d_ws + 256;
  char* Alo = Ahi + (size_t)M_DIM * K_DIM;          // 32 MB each
  char* Bq  = Alo + (size_t)M_DIM * K_DIM;          // 64 MB
  // ws: 256 B + 32 + 32 + 64 MB = 128 MB

  // zero BOTH scalars: ws is re-poisoned to 0xAA (0xAAAAAAAA would win atomicMax!)
  hipMemsetAsync(d_ws, 0, 16, stream);
  reduce_kernel<<<dim3(2048), dim3(256), 0, stream>>>(W, x, gsum, xmax,
                                                      (N_DIM * K_DIM) / 4,
                                                      (M_DIM * K_DIM) / 4);
  prep_kernel<<<dim3(2048), dim3(256), 0, stream>>>(W, x, gsum, xmax, Bq, Ahi, Alo,
                                                    (N_DIM * K_DIM) / 4,
                                                    (M_DIM * K_DIM) / 4);
  gemm_kernel<<<dim3((M_DIM / BM) * (N_DIM / BN)), dim3(512), 0, stream>>>(Ahi, Alo, Bq, xmax, C);
}